// Round 7
// baseline (72.828 us; speedup 1.0000x reference)
//
#include <hip/hip_runtime.h>
#include <hip/hip_bf16.h>

#define Bsz 8
#define Tsz 2048
#define Csz 1024
#define HSsz 64
#define NQ 192   // 3*hs

typedef __attribute__((ext_vector_type(8))) short short8v;
typedef __attribute__((ext_vector_type(4))) float f32x4;
typedef unsigned short ushortT;
typedef unsigned int uintT;

// fp32 -> bf16 round-to-nearest-even (bit pattern)
__device__ __forceinline__ unsigned int f2bf(float f) {
    union { float f; unsigned int u; } v; v.f = f;
    return (v.u + 0x7fffu + ((v.u >> 16) & 1u)) >> 16;
}

__device__ __forceinline__ unsigned int pk2bf(float lo, float hi) {
    union { __hip_bfloat162 h2; unsigned int u; } cv;
    cv.h2 = __float22bfloat162_rn(float2{lo, hi});
    return cv.u;
}

// ------------- prep: pack qkv_w B-frags (blocks 0..95) + W2 A-frags (blocks 96..127) -------------
__global__ __launch_bounds__(256) void k_prep(const float* __restrict__ qw,
                                              const float* __restrict__ pw,
                                              ushortT* __restrict__ wB,
                                              ushortT* __restrict__ w2a) {
    const int blk = blockIdx.x;
    if (blk < 96) {
        int idx = blk * 256 + threadIdx.x;      // 24576 threads = 32ks*12jt*64l
        int l = idx & 63;
        int ksjt = idx >> 6;
        int jt = ksjt % 12, ks = ksjt / 12;
        int j = jt * 16 + (l & 15);
        int k = ks * 32 + (l >> 4) * 8;
        const float* src = &qw[j * Csz + k];
        float4 a = *(const float4*)src;
        float4 b = *(const float4*)(src + 4);
        uint4 o;
        o.x = f2bf(a.x) | (f2bf(a.y) << 16);
        o.y = f2bf(a.z) | (f2bf(a.w) << 16);
        o.z = f2bf(b.x) | (f2bf(b.y) << 16);
        o.w = f2bf(b.z) | (f2bf(b.w) << 16);
        *(uint4*)&wB[(size_t)idx * 8] = o;
    } else {
        int idx = (blk - 96) * 256 + threadIdx.x;   // 0..8191 = 2ks*64m*64l
        int l = idx & 63;
        int rest = idx >> 6;
        int m = rest & 63, ks = rest >> 6;
        int c = m * 16 + (l & 15);
        int d0 = ks * 32 + (l >> 4) * 8;
        float s0 = 0, s1 = 0, s2 = 0, s3 = 0, s4 = 0, s5 = 0, s6 = 0, s7 = 0;
#pragma unroll
        for (int hh = 0; hh < 16; ++hh) {
            const float* p = &pw[c * Csz + hh * HSsz + d0];
            float4 x = *(const float4*)p;
            float4 y = *(const float4*)(p + 4);
            s0 += x.x; s1 += x.y; s2 += x.z; s3 += x.w;
            s4 += y.x; s5 += y.y; s6 += y.z; s7 += y.w;
        }
        uint4 o;
        o.x = f2bf(s0) | (f2bf(s1) << 16);
        o.y = f2bf(s2) | (f2bf(s3) << 16);
        o.z = f2bf(s4) | (f2bf(s5) << 16);
        o.w = f2bf(s6) | (f2bf(s7) << 16);
        *(uint4*)&w2a[(size_t)idx * 8] = o;
    }
}

// ---------------- qkv GEMM via bf16 MFMA, LDS-staged A (128-col chunks, 8 barriers) ----
// 512 thr = 8 waves: wm(2 row-slabs) x wn(4 col-groups of 48). Block tile 32x192.
// Emits fragment-packed Qf/Kf/Vf:
// Qf/Kf: [(M16*2+ks)*64+l][8] = X[M16*16 + (l&15)][ks*32 + (l>>4)*8 + b]
// Vf:    [((b*64+s32)*4+n)*64+l][8] = V[s32*32 + (l>>4)*8 + b][16n + (l&15)]
__global__ __launch_bounds__(512, 4) void k_qkv_mfma(const float* __restrict__ ids,
                                                     const ushortT* __restrict__ wB,
                                                     const float* __restrict__ bias,
                                                     ushortT* __restrict__ Qf,
                                                     ushortT* __restrict__ Kf,
                                                     ushortT* __restrict__ Vf) {
    __shared__ float sA[2][32 * 132];  // 33.8 KB dbuf; epilogue overlays Lqk/Lv in sA[0]
    uintT* Lqk = (uintT*)&sA[0][0];    // [32 t][68 uint] (ushort view [32][136], j 0..127)
    uintT* Lv  = Lqk + 32 * 68;        // [64 d][20 uint] (t-pairs)

    const int tid = threadIdx.x;
    const int wv  = tid >> 6;
    const int l   = tid & 63;
    const int wm  = wv >> 2;        // 0..1 row slab
    const int wn  = wv & 3;         // 0..3 -> jt0 = wn*3
    const int lg  = l >> 4, ll = l & 15;

    const int row0 = blockIdx.x * 32;

    const int srow = tid >> 4;          // 0..31
    const int scol = (tid & 15) * 8;    // 0..120
    const float* gsrc = ids + (size_t)(row0 + srow) * Csz + scol;

    const int afrow = wm * 16 + ll;

    f32x4 acc[3];
    acc[0] = acc[1] = acc[2] = (f32x4){0.f, 0.f, 0.f, 0.f};

    float4 st0 = *(const float4*)gsrc;
    float4 st1 = *(const float4*)(gsrc + 4);

    const ushortT* bbase_p = wB + ((size_t)(wn * 3) * 64 + l) * 8;  // +ks*6144

    for (int c = 0; c < 8; ++c) {
        float* bufp = &sA[c & 1][0];
        float* wp = &bufp[srow * 132 + scol];
        *(float4*)wp = st0;
        *(float4*)(wp + 4) = st1;
        __syncthreads();                    // lgkm drain makes chunk visible; dbuf => 1 barrier/chunk
        if (c < 7) {                        // prefetch AFTER barrier so the vmcnt(0) drain
            st0 = *(const float4*)(gsrc + (c + 1) * 128);        // doesn't stall on it;
            st1 = *(const float4*)(gsrc + (c + 1) * 128 + 4);    // lands under compute below
        }
#pragma unroll
        for (int kk = 0; kk < 4; ++kk) {
            const ushortT* bp = bbase_p + (size_t)(4 * c + kk) * 6144;
            short8v b0 = *(const short8v*)(bp);
            short8v b1 = *(const short8v*)(bp + 512);
            short8v b2 = *(const short8v*)(bp + 1024);

            const float* ap = &bufp[afrow * 132 + kk * 32 + lg * 8];
            float4 a0 = *(const float4*)ap;
            float4 a1 = *(const float4*)(ap + 4);
            union { short8v s; unsigned int u[4]; } af;
            af.u[0] = pk2bf(a0.x, a0.y); af.u[1] = pk2bf(a0.z, a0.w);
            af.u[2] = pk2bf(a1.x, a1.y); af.u[3] = pk2bf(a1.z, a1.w);

            acc[0] = __builtin_amdgcn_mfma_f32_16x16x32_bf16(af.s, b0, acc[0], 0, 0, 0);
            acc[1] = __builtin_amdgcn_mfma_f32_16x16x32_bf16(af.s, b1, acc[1], 0, 0, 0);
            acc[2] = __builtin_amdgcn_mfma_f32_16x16x32_bf16(af.s, b2, acc[2], 0, 0, 0);
        }
    }
    __syncthreads();   // all reads of sA done before epilogue overlay

    // ---- epilogue: transpose through LDS, emit fragment-packed outputs ----
    const int crow_l = wm * 16 + lg * 4;    // local t row (base of 4)
    ushortT* L16 = (ushortT*)Lqk;
#pragma unroll
    for (int n = 0; n < 3; ++n) {
        const int jb = wn * 3 + n;
        const int j  = jb * 16 + ll;
        const float bj = bias[j];
        float v0 = acc[n][0] + bj, v1 = acc[n][1] + bj;
        float v2 = acc[n][2] + bj, v3 = acc[n][3] + bj;
        if (jb < 8) {   // Q (j 0..63) and K (j 64..127): write along t
            ushortT* p = &L16[crow_l * 136 + j];
            p[0]   = (ushortT)f2bf(v0);
            p[136] = (ushortT)f2bf(v1);
            p[272] = (ushortT)f2bf(v2);
            p[408] = (ushortT)f2bf(v3);
        } else {        // V: d-major, t-pairs
            uintT* p = &Lv[(j - 128) * 20 + (crow_l >> 1)];
            p[0] = pk2bf(v0, v1);
            p[1] = pk2bf(v2, v3);
        }
    }
    __syncthreads();

    const int l2 = tid & 63, ll2 = l2 & 15, lg2 = l2 >> 4;
    if (tid < 256) {
        const int ks = (tid >> 6) & 1, m = tid >> 7;
        uint4 q = *(const uint4*)&Lqk[(m * 16 + ll2) * 68 + ks * 16 + lg2 * 4];
        *(uint4*)&Qf[(((size_t)(row0 >> 4) + m) * 2 + ks) * 512 + l2 * 8] = q;
        const int n = tid >> 6;     // 0..3
        uint4 v = *(const uint4*)&Lv[(n * 16 + ll2) * 20 + lg2 * 4];
        const int bb = row0 >> 11, s32 = (row0 >> 5) & 63;
        *(uint4*)&Vf[((((size_t)bb * 64 + s32) * 4 + n) * 64 + l2) * 8] = v;
    } else {
        const int ks = (tid >> 6) & 1, m = (tid >> 7) & 1;
        uint4 k = *(const uint4*)&Lqk[(m * 16 + ll2) * 68 + 32 + ks * 16 + lg2 * 4];
        *(uint4*)&Kf[(((size_t)(row0 >> 4) + m) * 2 + ks) * 512 + l2 * 8] = k;
    }
}

// ---------------- fused causal attention + output projection (no softmax) ----------------
// 32 q-rows per wave. Heavy block (r<32): strip si=63-r, 4-way tile split.
// Light block: strips (31-rr, rr) — constant 17 tiles — each 2-way split.
// After O-combine in LDS, the W2 projection runs in-block: A=w2a frags (L2),
// B=h frags packed from s_o; D gives 4 consecutive c per lane -> float4 out stores.
__global__ __launch_bounds__(256, 3) void k_attn_proj(const ushortT* __restrict__ Qf,
                                                      const ushortT* __restrict__ Kf,
                                                      const ushortT* __restrict__ Vf,
                                                      const ushortT* __restrict__ w2a,
                                                      const float* __restrict__ pb,
                                                      float* __restrict__ out) {
    __shared__ uintT su[4 * 2 * 16 * 36];   // per-wave S^T bounce, 18.4 KB
    __shared__ float s_o[4][32 * 68];       // per-wave partial O, padded, 34.8 KB

    const int tid = threadIdx.x;
    const int w  = tid >> 6;
    const int l  = tid & 63;
    const int lg = l >> 4;
    const int ll = l & 15;

    const int u = blockIdx.x;
    const int b = u / 48;
    const int r = u - b * 48;

    int si, sub, nsub;
    const bool heavy = (r < 32);
    if (heavy) { si = 63 - r; sub = w; nsub = 4; }
    else {
        const int rr = r - 32;
        si = (w < 2) ? (31 - rr) : rr;
        sub = w & 1; nsub = 2;
    }
    const int nT  = (si >> 1) + 1;          // 64-key tiles for this strip
    const int qn  = nT / nsub, rem = nT % nsub;
    const int t0  = sub * qn + (sub < rem ? sub : rem);
    const int cnt = qn + (sub < rem ? 1 : 0);

    const int gq = b * 128 + si * 2;        // global 16-row group of first q rows

    short8v qf[2][2];
#pragma unroll
    for (int mt = 0; mt < 2; ++mt)
#pragma unroll
        for (int ks = 0; ks < 2; ++ks)
            qf[mt][ks] = *(const short8v*)&Qf[(((size_t)gq + mt) * 2 + ks) * 512 + l * 8];

    f32x4 oacc[2][4];
#pragma unroll
    for (int mt = 0; mt < 2; ++mt)
#pragma unroll
        for (int n = 0; n < 4; ++n) oacc[mt][n] = (f32x4){0.f, 0.f, 0.f, 0.f};

    for (int tile = t0; tile < t0 + cnt; ++tile) {
        const int gs = b * 128 + tile * 4;
        short8v kf[4][2];
#pragma unroll
        for (int ms = 0; ms < 4; ++ms) {
            const ushortT* kp = &Kf[(((size_t)gs + ms) * 2) * 512 + l * 8];
            kf[ms][0] = *(const short8v*)kp;
            kf[ms][1] = *(const short8v*)(kp + 512);
        }
        f32x4 sacc[4][2];
#pragma unroll
        for (int ms = 0; ms < 4; ++ms)
#pragma unroll
            for (int mt = 0; mt < 2; ++mt) sacc[ms][mt] = (f32x4){0.f, 0.f, 0.f, 0.f};
#pragma unroll
        for (int ms = 0; ms < 4; ++ms)
#pragma unroll
            for (int mt = 0; mt < 2; ++mt) {
                sacc[ms][mt] = __builtin_amdgcn_mfma_f32_16x16x32_bf16(kf[ms][0], qf[mt][0], sacc[ms][mt], 0, 0, 0);
                sacc[ms][mt] = __builtin_amdgcn_mfma_f32_16x16x32_bf16(kf[ms][1], qf[mt][1], sacc[ms][mt], 0, 0, 0);
            }
        if (tile == nT - 1) {   // causal mask on diagonal tile
#pragma unroll
            for (int ms = 0; ms < 4; ++ms)
#pragma unroll
                for (int mt = 0; mt < 2; ++mt) {
                    const int tg = si * 32 + mt * 16 + ll;
#pragma unroll
                    for (int rr2 = 0; rr2 < 4; ++rr2) {
                        int sg = tile * 64 + ms * 16 + 4 * lg + rr2;
                        if (sg > tg) sacc[ms][mt][rr2] = 0.f;
                    }
                }
        }
        // bounce S^T -> bf16 A-frags (per-wave LDS, no barrier)
#pragma unroll
        for (int mt = 0; mt < 2; ++mt)
#pragma unroll
            for (int ms = 0; ms < 4; ++ms) {
                uint2 pk;
                pk.x = pk2bf(sacc[ms][mt][0], sacc[ms][mt][1]);
                pk.y = pk2bf(sacc[ms][mt][2], sacc[ms][mt][3]);
                *(uint2*)&su[((w * 2 + mt) * 16 + ll) * 36 + ms * 8 + 2 * lg] = pk;
            }
        union { uint4 u4; short8v s; } pa[2][2];
#pragma unroll
        for (int mt = 0; mt < 2; ++mt)
#pragma unroll
            for (int h = 0; h < 2; ++h)
                pa[mt][h].u4 = *(const uint4*)&su[((w * 2 + mt) * 16 + ll) * 36 + h * 16 + lg * 4];

        const int gv = b * 64 + tile * 2;
        short8v vf[2][4];
#pragma unroll
        for (int h = 0; h < 2; ++h)
#pragma unroll
            for (int n = 0; n < 4; ++n)
                vf[h][n] = *(const short8v*)&Vf[((((size_t)gv + h) * 4 + n) * 64 + l) * 8];
#pragma unroll
        for (int mt = 0; mt < 2; ++mt)
#pragma unroll
            for (int n = 0; n < 4; ++n) {
                oacc[mt][n] = __builtin_amdgcn_mfma_f32_16x16x32_bf16(pa[mt][0].s, vf[0][n], oacc[mt][n], 0, 0, 0);
                oacc[mt][n] = __builtin_amdgcn_mfma_f32_16x16x32_bf16(pa[mt][1].s, vf[1][n], oacc[mt][n], 0, 0, 0);
            }
    }

    // partial O to LDS
#pragma unroll
    for (int mt = 0; mt < 2; ++mt)
#pragma unroll
        for (int n = 0; n < 4; ++n)
#pragma unroll
            for (int rr2 = 0; rr2 < 4; ++rr2)
                s_o[w][(mt * 16 + 4 * lg + rr2) * 68 + 16 * n + ll] = oacc[mt][n][rr2];
    __syncthreads();

    // ---- fused projection: out[t][c] = sum_d h[t][d] * W2[d][c] + pb[c] ----
    int pstrip, nsum, wb0, mstart, mcount;
    if (heavy) { pstrip = si; nsum = 4; wb0 = 0; mstart = w * 16; mcount = 16; }
    else {
        const int rr = r - 32;
        pstrip = (w < 2) ? (31 - rr) : rr;
        nsum = 2; wb0 = (w < 2) ? 0 : 2;
        mstart = (w & 1) * 32; mcount = 32;
    }

    union { short8v s; unsigned int u[4]; } hbf[2][2];
#pragma unroll
    for (int mt = 0; mt < 2; ++mt)
#pragma unroll
        for (int ks = 0; ks < 2; ++ks) {
            float4 A = {0.f, 0.f, 0.f, 0.f}, B2 = {0.f, 0.f, 0.f, 0.f};
            for (int w2 = wb0; w2 < wb0 + nsum; ++w2) {
                const float* p = &s_o[w2][(mt * 16 + ll) * 68 + ks * 32 + lg * 8];
                const float4 x = *(const float4*)p;
                const float4 y = *(const float4*)(p + 4);
                A.x += x.x; A.y += x.y; A.z += x.z; A.w += x.w;
                B2.x += y.x; B2.y += y.y; B2.z += y.z; B2.w += y.w;
            }
            hbf[mt][ks].u[0] = pk2bf(A.x, A.y);
            hbf[mt][ks].u[1] = pk2bf(A.z, A.w);
            hbf[mt][ks].u[2] = pk2bf(B2.x, B2.y);
            hbf[mt][ks].u[3] = pk2bf(B2.z, B2.w);
        }

    const int gt = b * Tsz + pstrip * 32;
    const int crow = lg * 4;
#pragma unroll 4
    for (int m = mstart; m < mstart + mcount; ++m) {
        const ushortT* ap = w2a + (size_t)(m * 64 + l) * 8;
        short8v a0 = *(const short8v*)ap;
        short8v a1 = *(const short8v*)(ap + 32768);   // ks=1 plane: 64*64*8
        const float4 pv = *(const float4*)&pb[m * 16 + crow];
#pragma unroll
        for (int mt = 0; mt < 2; ++mt) {
            f32x4 acc = (f32x4){0.f, 0.f, 0.f, 0.f};
            acc = __builtin_amdgcn_mfma_f32_16x16x32_bf16(a0, hbf[mt][0].s, acc, 0, 0, 0);
            acc = __builtin_amdgcn_mfma_f32_16x16x32_bf16(a1, hbf[mt][1].s, acc, 0, 0, 0);
            float4 o;
            o.x = acc[0] + pv.x; o.y = acc[1] + pv.y;
            o.z = acc[2] + pv.z; o.w = acc[3] + pv.w;
            *(float4*)&out[(size_t)(gt + mt * 16 + ll) * Csz + m * 16 + crow] = o;
        }
    }
}

extern "C" void kernel_launch(void* const* d_in, const int* in_sizes, int n_in,
                              void* d_out, int out_size, void* d_ws, size_t ws_size,
                              hipStream_t stream) {
    const float* ids    = (const float*)d_in[0];
    const float* qkv_w  = (const float*)d_in[1];
    const float* qkv_b  = (const float*)d_in[2];
    const float* proj_w = (const float*)d_in[3];
    const float* proj_b = (const float*)d_in[4];
    float* out = (float*)d_out;

    ushortT* Qf  = (ushortT*)d_ws;          // 2 MB fragment-packed
    ushortT* Kf  = Qf + 16384 * HSsz;       // 2 MB
    ushortT* Vf  = Kf + 16384 * HSsz;       // 2 MB
    ushortT* wB  = Vf + 16384 * HSsz;       // 384 KB
    ushortT* w2a = wB + 196608;             // 128 KB

    hipLaunchKernelGGL(k_prep,      dim3(128), dim3(256), 0, stream, qkv_w, proj_w, wB, w2a);
    hipLaunchKernelGGL(k_qkv_mfma,  dim3(512), dim3(512), 0, stream, ids, wB, qkv_b, Qf, Kf, Vf);
    hipLaunchKernelGGL(k_attn_proj, dim3(384), dim3(256), 0, stream, Qf, Kf, Vf, w2a, proj_b, out);
}

// Round 8
// 63.438 us; speedup vs baseline: 1.1480x; 1.1480x over previous
//
#include <hip/hip_runtime.h>
#include <hip/hip_bf16.h>

#define Bsz 8
#define Tsz 2048
#define Csz 1024
#define HSsz 64
#define NQ 192   // 3*hs

typedef __attribute__((ext_vector_type(8))) short short8v;
typedef __attribute__((ext_vector_type(4))) float f32x4;
typedef unsigned short ushortT;
typedef unsigned int uintT;

// fp32 -> bf16 round-to-nearest-even (bit pattern)
__device__ __forceinline__ unsigned int f2bf(float f) {
    union { float f; unsigned int u; } v; v.f = f;
    return (v.u + 0x7fffu + ((v.u >> 16) & 1u)) >> 16;
}

__device__ __forceinline__ unsigned int pk2bf(float lo, float hi) {
    union { __hip_bfloat162 h2; unsigned int u; } cv;
    cv.h2 = __float22bfloat162_rn(float2{lo, hi});
    return cv.u;
}

// ------------- prep: pack qkv_w B-frags (blocks 0..95) + W2 A-frags (blocks 96..127) -------------
__global__ __launch_bounds__(256) void k_prep(const float* __restrict__ qw,
                                              const float* __restrict__ pw,
                                              ushortT* __restrict__ wB,
                                              ushortT* __restrict__ w2a) {
    const int blk = blockIdx.x;
    if (blk < 96) {
        int idx = blk * 256 + threadIdx.x;      // 24576 threads = 32ks*12jt*64l
        int l = idx & 63;
        int ksjt = idx >> 6;
        int jt = ksjt % 12, ks = ksjt / 12;
        int j = jt * 16 + (l & 15);
        int k = ks * 32 + (l >> 4) * 8;
        const float* src = &qw[j * Csz + k];
        float4 a = *(const float4*)src;
        float4 b = *(const float4*)(src + 4);
        uint4 o;
        o.x = f2bf(a.x) | (f2bf(a.y) << 16);
        o.y = f2bf(a.z) | (f2bf(a.w) << 16);
        o.z = f2bf(b.x) | (f2bf(b.y) << 16);
        o.w = f2bf(b.z) | (f2bf(b.w) << 16);
        *(uint4*)&wB[(size_t)idx * 8] = o;
    } else {
        int idx = (blk - 96) * 256 + threadIdx.x;   // 0..8191 = 2ks*64m*64l
        int l = idx & 63;
        int rest = idx >> 6;
        int m = rest & 63, ks = rest >> 6;
        int c = m * 16 + (l & 15);
        int d0 = ks * 32 + (l >> 4) * 8;
        float s0 = 0, s1 = 0, s2 = 0, s3 = 0, s4 = 0, s5 = 0, s6 = 0, s7 = 0;
#pragma unroll
        for (int hh = 0; hh < 16; ++hh) {
            const float* p = &pw[c * Csz + hh * HSsz + d0];
            float4 x = *(const float4*)p;
            float4 y = *(const float4*)(p + 4);
            s0 += x.x; s1 += x.y; s2 += x.z; s3 += x.w;
            s4 += y.x; s5 += y.y; s6 += y.z; s7 += y.w;
        }
        uint4 o;
        o.x = f2bf(s0) | (f2bf(s1) << 16);
        o.y = f2bf(s2) | (f2bf(s3) << 16);
        o.z = f2bf(s4) | (f2bf(s5) << 16);
        o.w = f2bf(s6) | (f2bf(s7) << 16);
        *(uint4*)&w2a[(size_t)idx * 8] = o;
    }
}

// ---------------- qkv GEMM via bf16 MFMA, LDS-staged A (128-col chunks, 8 barriers) ----
// 512 thr = 8 waves: wm(2 row-slabs) x wn(4 col-groups of 48). Block tile 32x192.
// Emits fragment-packed Qf/Kf/Vf:
// Qf/Kf: [(M16*2+ks)*64+l][8] = X[M16*16 + (l&15)][ks*32 + (l>>4)*8 + b]
// Vf:    [((b*64+s32)*4+n)*64+l][8] = V[s32*32 + (l>>4)*8 + b][16n + (l&15)]
__global__ __launch_bounds__(512, 4) void k_qkv_mfma(const float* __restrict__ ids,
                                                     const ushortT* __restrict__ wB,
                                                     const float* __restrict__ bias,
                                                     ushortT* __restrict__ Qf,
                                                     ushortT* __restrict__ Kf,
                                                     ushortT* __restrict__ Vf) {
    __shared__ float sA[2][32 * 132];  // 33.8 KB dbuf; epilogue overlays Lqk/Lv in sA[0]
    uintT* Lqk = (uintT*)&sA[0][0];    // [32 t][68 uint] (ushort view [32][136], j 0..127)
    uintT* Lv  = Lqk + 32 * 68;        // [64 d][20 uint] (t-pairs)

    const int tid = threadIdx.x;
    const int wv  = tid >> 6;
    const int l   = tid & 63;
    const int wm  = wv >> 2;        // 0..1 row slab
    const int wn  = wv & 3;         // 0..3 -> jt0 = wn*3
    const int lg  = l >> 4, ll = l & 15;

    const int row0 = blockIdx.x * 32;

    const int srow = tid >> 4;          // 0..31
    const int scol = (tid & 15) * 8;    // 0..120
    const float* gsrc = ids + (size_t)(row0 + srow) * Csz + scol;

    const int afrow = wm * 16 + ll;

    f32x4 acc[3];
    acc[0] = acc[1] = acc[2] = (f32x4){0.f, 0.f, 0.f, 0.f};

    float4 st0 = *(const float4*)gsrc;
    float4 st1 = *(const float4*)(gsrc + 4);

    const ushortT* bbase_p = wB + ((size_t)(wn * 3) * 64 + l) * 8;  // +ks*6144

    for (int c = 0; c < 8; ++c) {
        float* bufp = &sA[c & 1][0];
        float* wp = &bufp[srow * 132 + scol];
        *(float4*)wp = st0;
        *(float4*)(wp + 4) = st1;
        __syncthreads();                    // lgkm drain makes chunk visible; dbuf => 1 barrier/chunk
        if (c < 7) {                        // prefetch AFTER barrier so the vmcnt(0) drain
            st0 = *(const float4*)(gsrc + (c + 1) * 128);        // doesn't stall on it;
            st1 = *(const float4*)(gsrc + (c + 1) * 128 + 4);    // lands under compute below
        }
#pragma unroll
        for (int kk = 0; kk < 4; ++kk) {
            const ushortT* bp = bbase_p + (size_t)(4 * c + kk) * 6144;
            short8v b0 = *(const short8v*)(bp);
            short8v b1 = *(const short8v*)(bp + 512);
            short8v b2 = *(const short8v*)(bp + 1024);

            const float* ap = &bufp[afrow * 132 + kk * 32 + lg * 8];
            float4 a0 = *(const float4*)ap;
            float4 a1 = *(const float4*)(ap + 4);
            union { short8v s; unsigned int u[4]; } af;
            af.u[0] = pk2bf(a0.x, a0.y); af.u[1] = pk2bf(a0.z, a0.w);
            af.u[2] = pk2bf(a1.x, a1.y); af.u[3] = pk2bf(a1.z, a1.w);

            acc[0] = __builtin_amdgcn_mfma_f32_16x16x32_bf16(af.s, b0, acc[0], 0, 0, 0);
            acc[1] = __builtin_amdgcn_mfma_f32_16x16x32_bf16(af.s, b1, acc[1], 0, 0, 0);
            acc[2] = __builtin_amdgcn_mfma_f32_16x16x32_bf16(af.s, b2, acc[2], 0, 0, 0);
        }
    }
    __syncthreads();   // all reads of sA done before epilogue overlay

    // ---- epilogue: transpose through LDS, emit fragment-packed outputs ----
    const int crow_l = wm * 16 + lg * 4;    // local t row (base of 4)
    ushortT* L16 = (ushortT*)Lqk;
#pragma unroll
    for (int n = 0; n < 3; ++n) {
        const int jb = wn * 3 + n;
        const int j  = jb * 16 + ll;
        const float bj = bias[j];
        float v0 = acc[n][0] + bj, v1 = acc[n][1] + bj;
        float v2 = acc[n][2] + bj, v3 = acc[n][3] + bj;
        if (jb < 8) {   // Q (j 0..63) and K (j 64..127): write along t
            ushortT* p = &L16[crow_l * 136 + j];
            p[0]   = (ushortT)f2bf(v0);
            p[136] = (ushortT)f2bf(v1);
            p[272] = (ushortT)f2bf(v2);
            p[408] = (ushortT)f2bf(v3);
        } else {        // V: d-major, t-pairs
            uintT* p = &Lv[(j - 128) * 20 + (crow_l >> 1)];
            p[0] = pk2bf(v0, v1);
            p[1] = pk2bf(v2, v3);
        }
    }
    __syncthreads();

    const int l2 = tid & 63, ll2 = l2 & 15, lg2 = l2 >> 4;
    if (tid < 256) {
        const int ks = (tid >> 6) & 1, m = tid >> 7;
        uint4 q = *(const uint4*)&Lqk[(m * 16 + ll2) * 68 + ks * 16 + lg2 * 4];
        *(uint4*)&Qf[(((size_t)(row0 >> 4) + m) * 2 + ks) * 512 + l2 * 8] = q;
        const int n = tid >> 6;     // 0..3
        uint4 v = *(const uint4*)&Lv[(n * 16 + ll2) * 20 + lg2 * 4];
        const int bb = row0 >> 11, s32 = (row0 >> 5) & 63;
        *(uint4*)&Vf[((((size_t)bb * 64 + s32) * 4 + n) * 64 + l2) * 8] = v;
    } else {
        const int ks = (tid >> 6) & 1, m = (tid >> 7) & 1;
        uint4 k = *(const uint4*)&Lqk[(m * 16 + ll2) * 68 + 32 + ks * 16 + lg2 * 4];
        *(uint4*)&Kf[(((size_t)(row0 >> 4) + m) * 2 + ks) * 512 + l2 * 8] = k;
    }
}

// ---------------- fused causal attention via bf16 MFMA (no softmax) ----------------
// 32 q-rows per wave. Heavy block (r<32): strip si=63-r, 4-way tile split.
// Light block: strips (31-rr, rr) — constant 17 tiles — each 2-way split.
// All frag loads coalesced from packed Qf/Kf/Vf; swapped QK^T; per-wave S bounce.
__global__ __launch_bounds__(256, 3) void k_attn_mfma(const ushortT* __restrict__ Qf,
                                                      const ushortT* __restrict__ Kf,
                                                      const ushortT* __restrict__ Vf,
                                                      ushortT* __restrict__ hf) {
    __shared__ uintT su[4 * 2 * 16 * 36];   // per-wave S^T bounce, 18.4 KB
    __shared__ float s_o[4][32 * 68];       // per-wave partial O, padded, 34.8 KB

    const int tid = threadIdx.x;
    const int w  = tid >> 6;
    const int l  = tid & 63;
    const int lg = l >> 4;
    const int ll = l & 15;

    const int u = blockIdx.x;
    const int b = u / 48;
    const int r = u - b * 48;

    int si, sub, nsub;
    const bool heavy = (r < 32);
    if (heavy) { si = 63 - r; sub = w; nsub = 4; }
    else {
        const int rr = r - 32;
        si = (w < 2) ? (31 - rr) : rr;
        sub = w & 1; nsub = 2;
    }
    const int nT  = (si >> 1) + 1;          // 64-key tiles for this strip
    const int qn  = nT / nsub, rem = nT % nsub;
    const int t0  = sub * qn + (sub < rem ? sub : rem);
    const int cnt = qn + (sub < rem ? 1 : 0);

    const int gq = b * 128 + si * 2;        // global 16-row group of first q rows

    short8v qf[2][2];
#pragma unroll
    for (int mt = 0; mt < 2; ++mt)
#pragma unroll
        for (int ks = 0; ks < 2; ++ks)
            qf[mt][ks] = *(const short8v*)&Qf[(((size_t)gq + mt) * 2 + ks) * 512 + l * 8];

    f32x4 oacc[2][4];
#pragma unroll
    for (int mt = 0; mt < 2; ++mt)
#pragma unroll
        for (int n = 0; n < 4; ++n) oacc[mt][n] = (f32x4){0.f, 0.f, 0.f, 0.f};

    for (int tile = t0; tile < t0 + cnt; ++tile) {
        const int gs = b * 128 + tile * 4;
        short8v kf[4][2];
#pragma unroll
        for (int ms = 0; ms < 4; ++ms) {
            const ushortT* kp = &Kf[(((size_t)gs + ms) * 2) * 512 + l * 8];
            kf[ms][0] = *(const short8v*)kp;
            kf[ms][1] = *(const short8v*)(kp + 512);
        }
        f32x4 sacc[4][2];
#pragma unroll
        for (int ms = 0; ms < 4; ++ms)
#pragma unroll
            for (int mt = 0; mt < 2; ++mt) sacc[ms][mt] = (f32x4){0.f, 0.f, 0.f, 0.f};
#pragma unroll
        for (int ms = 0; ms < 4; ++ms)
#pragma unroll
            for (int mt = 0; mt < 2; ++mt) {
                sacc[ms][mt] = __builtin_amdgcn_mfma_f32_16x16x32_bf16(kf[ms][0], qf[mt][0], sacc[ms][mt], 0, 0, 0);
                sacc[ms][mt] = __builtin_amdgcn_mfma_f32_16x16x32_bf16(kf[ms][1], qf[mt][1], sacc[ms][mt], 0, 0, 0);
            }
        if (tile == nT - 1) {   // causal mask on diagonal tile
#pragma unroll
            for (int ms = 0; ms < 4; ++ms)
#pragma unroll
                for (int mt = 0; mt < 2; ++mt) {
                    const int tg = si * 32 + mt * 16 + ll;
#pragma unroll
                    for (int rr2 = 0; rr2 < 4; ++rr2) {
                        int sg = tile * 64 + ms * 16 + 4 * lg + rr2;
                        if (sg > tg) sacc[ms][mt][rr2] = 0.f;
                    }
                }
        }
        // bounce S^T -> bf16 A-frags (per-wave LDS, no barrier)
#pragma unroll
        for (int mt = 0; mt < 2; ++mt)
#pragma unroll
            for (int ms = 0; ms < 4; ++ms) {
                uint2 pk;
                pk.x = pk2bf(sacc[ms][mt][0], sacc[ms][mt][1]);
                pk.y = pk2bf(sacc[ms][mt][2], sacc[ms][mt][3]);
                *(uint2*)&su[((w * 2 + mt) * 16 + ll) * 36 + ms * 8 + 2 * lg] = pk;
            }
        union { uint4 u4; short8v s; } pa[2][2];
#pragma unroll
        for (int mt = 0; mt < 2; ++mt)
#pragma unroll
            for (int h = 0; h < 2; ++h)
                pa[mt][h].u4 = *(const uint4*)&su[((w * 2 + mt) * 16 + ll) * 36 + h * 16 + lg * 4];

        const int gv = b * 64 + tile * 2;
        short8v vf[2][4];
#pragma unroll
        for (int h = 0; h < 2; ++h)
#pragma unroll
            for (int n = 0; n < 4; ++n)
                vf[h][n] = *(const short8v*)&Vf[((((size_t)gv + h) * 4 + n) * 64 + l) * 8];
#pragma unroll
        for (int mt = 0; mt < 2; ++mt)
#pragma unroll
            for (int n = 0; n < 4; ++n) {
                oacc[mt][n] = __builtin_amdgcn_mfma_f32_16x16x32_bf16(pa[mt][0].s, vf[0][n], oacc[mt][n], 0, 0, 0);
                oacc[mt][n] = __builtin_amdgcn_mfma_f32_16x16x32_bf16(pa[mt][1].s, vf[1][n], oacc[mt][n], 0, 0, 0);
            }
    }

    // partial O to LDS
#pragma unroll
    for (int mt = 0; mt < 2; ++mt)
#pragma unroll
        for (int n = 0; n < 4; ++n)
#pragma unroll
            for (int rr2 = 0; rr2 < 4; ++rr2)
                s_o[w][(mt * 16 + 4 * lg + rr2) * 68 + 16 * n + ll] = oacc[mt][n][rr2];
    __syncthreads();

    // combine + emit fragment-packed hf
    const int l2 = tid & 63, ll2 = l2 & 15, lg2 = l2 >> 4;
    const int ks = (tid >> 6) & 1, mt = tid >> 7;
    const int t = mt * 16 + ll2, dd = ks * 32 + lg2 * 8;
    if (heavy) {
        float4 A = {0, 0, 0, 0}, B2 = {0, 0, 0, 0};
#pragma unroll
        for (int w2 = 0; w2 < 4; ++w2) {
            const float4 x = *(const float4*)&s_o[w2][t * 68 + dd];
            const float4 y = *(const float4*)&s_o[w2][t * 68 + dd + 4];
            A.x += x.x; A.y += x.y; A.z += x.z; A.w += x.w;
            B2.x += y.x; B2.y += y.y; B2.z += y.z; B2.w += y.w;
        }
        uint4 o;
        o.x = pk2bf(A.x, A.y);  o.y = pk2bf(A.z, A.w);
        o.z = pk2bf(B2.x, B2.y); o.w = pk2bf(B2.z, B2.w);
        *(uint4*)&hf[(((size_t)(b * 128 + si * 2) + mt) * 2 + ks) * 512 + l2 * 8] = o;
    } else {
        const int rr = r - 32;
        const int sa = 31 - rr, sb = rr;
        float4 A = {0, 0, 0, 0}, B2 = {0, 0, 0, 0};
#pragma unroll
        for (int w2 = 0; w2 < 2; ++w2) {
            const float4 x = *(const float4*)&s_o[w2][t * 68 + dd];
            const float4 y = *(const float4*)&s_o[w2][t * 68 + dd + 4];
            A.x += x.x; A.y += x.y; A.z += x.z; A.w += x.w;
            B2.x += y.x; B2.y += y.y; B2.z += y.z; B2.w += y.w;
        }
        uint4 o;
        o.x = pk2bf(A.x, A.y);  o.y = pk2bf(A.z, A.w);
        o.z = pk2bf(B2.x, B2.y); o.w = pk2bf(B2.z, B2.w);
        *(uint4*)&hf[(((size_t)(b * 128 + sa * 2) + mt) * 2 + ks) * 512 + l2 * 8] = o;
        float4 C = {0, 0, 0, 0}, D2 = {0, 0, 0, 0};
#pragma unroll
        for (int w2 = 2; w2 < 4; ++w2) {
            const float4 x = *(const float4*)&s_o[w2][t * 68 + dd];
            const float4 y = *(const float4*)&s_o[w2][t * 68 + dd + 4];
            C.x += x.x; C.y += x.y; C.z += x.z; C.w += x.w;
            D2.x += y.x; D2.y += y.y; D2.z += y.z; D2.w += y.w;
        }
        uint4 o2;
        o2.x = pk2bf(C.x, C.y);  o2.y = pk2bf(C.z, C.w);
        o2.z = pk2bf(D2.x, D2.y); o2.w = pk2bf(D2.z, D2.w);
        *(uint4*)&hf[(((size_t)(b * 128 + sb * 2) + mt) * 2 + ks) * 512 + l2 * 8] = o2;
    }
}

// ---------------- out = h @ W2^T + pb via swapped-operand MFMA ----------------
// hf is fragment-packed: B-frag load is one coalesced dwordx4 per k-half.
__global__ __launch_bounds__(256) void k_proj_mfma(const ushortT* __restrict__ hf,
                                                   const ushortT* __restrict__ w2a,
                                                   const float* __restrict__ pb,
                                                   float* __restrict__ out) {
    const int tid = threadIdx.x;
    const int w = tid >> 6, l = tid & 63;
    const int t0 = blockIdx.x * 16;
    const size_t M = blockIdx.x;

    short8v hb0 = *(const short8v*)&hf[(M * 2 + 0) * 512 + l * 8];
    short8v hb1 = *(const short8v*)&hf[(M * 2 + 1) * 512 + l * 8];

    const int row = (l >> 4) * 4;
    const int tcol = l & 15;
    const size_t outrow = (size_t)(t0 + tcol) * Csz;

#pragma unroll 2
    for (int m = w * 16; m < w * 16 + 16; ++m) {
        const ushortT* ap = w2a + (size_t)(m * 64 + l) * 8;
        short8v a0 = *(const short8v*)ap;
        short8v a1 = *(const short8v*)(ap + 32768);   // ks=1 plane: 64*64*8
        f32x4 acc = (f32x4){0.f, 0.f, 0.f, 0.f};
        acc = __builtin_amdgcn_mfma_f32_16x16x32_bf16(a0, hb0, acc, 0, 0, 0);
        acc = __builtin_amdgcn_mfma_f32_16x16x32_bf16(a1, hb1, acc, 0, 0, 0);
        const int c0 = m * 16 + row;
        const float4 pv = *(const float4*)&pb[c0];
        float4 o;
        o.x = acc[0] + pv.x; o.y = acc[1] + pv.y;
        o.z = acc[2] + pv.z; o.w = acc[3] + pv.w;
        *(float4*)&out[outrow + c0] = o;
    }
}

extern "C" void kernel_launch(void* const* d_in, const int* in_sizes, int n_in,
                              void* d_out, int out_size, void* d_ws, size_t ws_size,
                              hipStream_t stream) {
    const float* ids    = (const float*)d_in[0];
    const float* qkv_w  = (const float*)d_in[1];
    const float* qkv_b  = (const float*)d_in[2];
    const float* proj_w = (const float*)d_in[3];
    const float* proj_b = (const float*)d_in[4];
    float* out = (float*)d_out;

    ushortT* Qf  = (ushortT*)d_ws;          // 2 MB fragment-packed
    ushortT* Kf  = Qf + 16384 * HSsz;       // 2 MB
    ushortT* Vf  = Kf + 16384 * HSsz;       // 2 MB
    ushortT* hf  = Vf + 16384 * HSsz;       // 2 MB
    ushortT* wB  = hf + 16384 * HSsz;       // 384 KB
    ushortT* w2a = wB + 196608;             // 128 KB

    hipLaunchKernelGGL(k_prep,      dim3(128),  dim3(256), 0, stream, qkv_w, proj_w, wB, w2a);
    hipLaunchKernelGGL(k_qkv_mfma,  dim3(512),  dim3(512), 0, stream, ids, wB, qkv_b, Qf, Kf, Vf);
    hipLaunchKernelGGL(k_attn_mfma, dim3(384),  dim3(256), 0, stream, Qf, Kf, Vf, hf);
    hipLaunchKernelGGL(k_proj_mfma, dim3(1024), dim3(256), 0, stream, hf, w2a, proj_b, out);
}

// Round 9
// 58.534 us; speedup vs baseline: 1.2442x; 1.0838x over previous
//
#include <hip/hip_runtime.h>
#include <hip/hip_bf16.h>

#define Bsz 8
#define Tsz 2048
#define Csz 1024
#define HSsz 64
#define NQ 192   // 3*hs

typedef __attribute__((ext_vector_type(8))) short short8v;
typedef __attribute__((ext_vector_type(4))) float f32x4;
typedef unsigned short ushortT;
typedef unsigned int uintT;

// fp32 -> bf16 round-to-nearest-even (bit pattern)
__device__ __forceinline__ unsigned int f2bf(float f) {
    union { float f; unsigned int u; } v; v.f = f;
    return (v.u + 0x7fffu + ((v.u >> 16) & 1u)) >> 16;
}

__device__ __forceinline__ unsigned int pk2bf(float lo, float hi) {
    union { __hip_bfloat162 h2; unsigned int u; } cv;
    cv.h2 = __float22bfloat162_rn(float2{lo, hi});
    return cv.u;
}

// ------------- prep: pack qkv_w B-frags (blocks 0..95) + W2 A-frags (blocks 96..127) -------------
__global__ __launch_bounds__(256) void k_prep(const float* __restrict__ qw,
                                              const float* __restrict__ pw,
                                              ushortT* __restrict__ wB,
                                              ushortT* __restrict__ w2a) {
    const int blk = blockIdx.x;
    if (blk < 96) {
        int idx = blk * 256 + threadIdx.x;      // 24576 threads = 32ks*12jt*64l
        int l = idx & 63;
        int ksjt = idx >> 6;
        int jt = ksjt % 12, ks = ksjt / 12;
        int j = jt * 16 + (l & 15);
        int k = ks * 32 + (l >> 4) * 8;
        const float* src = &qw[j * Csz + k];
        float4 a = *(const float4*)src;
        float4 b = *(const float4*)(src + 4);
        uint4 o;
        o.x = f2bf(a.x) | (f2bf(a.y) << 16);
        o.y = f2bf(a.z) | (f2bf(a.w) << 16);
        o.z = f2bf(b.x) | (f2bf(b.y) << 16);
        o.w = f2bf(b.z) | (f2bf(b.w) << 16);
        *(uint4*)&wB[(size_t)idx * 8] = o;
    } else {
        int idx = (blk - 96) * 256 + threadIdx.x;   // 0..8191 = 2ks*64m*64l
        int l = idx & 63;
        int rest = idx >> 6;
        int m = rest & 63, ks = rest >> 6;
        int c = m * 16 + (l & 15);
        int d0 = ks * 32 + (l >> 4) * 8;
        float s0 = 0, s1 = 0, s2 = 0, s3 = 0, s4 = 0, s5 = 0, s6 = 0, s7 = 0;
#pragma unroll
        for (int hh = 0; hh < 16; ++hh) {
            const float* p = &pw[c * Csz + hh * HSsz + d0];
            float4 x = *(const float4*)p;
            float4 y = *(const float4*)(p + 4);
            s0 += x.x; s1 += x.y; s2 += x.z; s3 += x.w;
            s4 += y.x; s5 += y.y; s6 += y.z; s7 += y.w;
        }
        uint4 o;
        o.x = f2bf(s0) | (f2bf(s1) << 16);
        o.y = f2bf(s2) | (f2bf(s3) << 16);
        o.z = f2bf(s4) | (f2bf(s5) << 16);
        o.w = f2bf(s6) | (f2bf(s7) << 16);
        *(uint4*)&w2a[(size_t)idx * 8] = o;
    }
}

// ---------------- qkv GEMM via bf16 MFMA, LDS-staged A (128-col chunks, 8 barriers) ----
// 512 thr = 8 waves: wm(2 row-slabs) x wn(4 col-groups of 48). Block tile 32x192.
// Emits fragment-packed Qf/Kf/Vf:
// Qf/Kf: [(M16*2+ks)*64+l][8] = X[M16*16 + (l&15)][ks*32 + (l>>4)*8 + b]
// Vf:    [((b*64+s32)*4+n)*64+l][8] = V[s32*32 + (l>>4)*8 + b][16n + (l&15)]
__global__ __launch_bounds__(512, 4) void k_qkv_mfma(const float* __restrict__ ids,
                                                     const ushortT* __restrict__ wB,
                                                     const float* __restrict__ bias,
                                                     ushortT* __restrict__ Qf,
                                                     ushortT* __restrict__ Kf,
                                                     ushortT* __restrict__ Vf) {
    __shared__ float sA[2][32 * 132];  // 33.8 KB dbuf; epilogue overlays Lqk/Lv in sA[0]
    uintT* Lqk = (uintT*)&sA[0][0];    // [32 t][68 uint] (ushort view [32][136], j 0..127)
    uintT* Lv  = Lqk + 32 * 68;        // [64 d][20 uint] (t-pairs)

    const int tid = threadIdx.x;
    const int wv  = tid >> 6;
    const int l   = tid & 63;
    const int wm  = wv >> 2;        // 0..1 row slab
    const int wn  = wv & 3;         // 0..3 -> jt0 = wn*3
    const int lg  = l >> 4, ll = l & 15;

    const int row0 = blockIdx.x * 32;

    const int srow = tid >> 4;          // 0..31
    const int scol = (tid & 15) * 8;    // 0..120
    const float* gsrc = ids + (size_t)(row0 + srow) * Csz + scol;

    const int afrow = wm * 16 + ll;

    f32x4 acc[3];
    acc[0] = acc[1] = acc[2] = (f32x4){0.f, 0.f, 0.f, 0.f};

    float4 st0 = *(const float4*)gsrc;
    float4 st1 = *(const float4*)(gsrc + 4);

    const ushortT* bbase_p = wB + ((size_t)(wn * 3) * 64 + l) * 8;  // +ks*6144

    for (int c = 0; c < 8; ++c) {
        float* bufp = &sA[c & 1][0];
        float* wp = &bufp[srow * 132 + scol];
        *(float4*)wp = st0;
        *(float4*)(wp + 4) = st1;
        __syncthreads();                    // lgkm drain makes chunk visible; dbuf => 1 barrier/chunk
        if (c < 7) {                        // prefetch AFTER barrier so the vmcnt(0) drain
            st0 = *(const float4*)(gsrc + (c + 1) * 128);        // doesn't stall on it;
            st1 = *(const float4*)(gsrc + (c + 1) * 128 + 4);    // lands under compute below
        }
#pragma unroll
        for (int kk = 0; kk < 4; ++kk) {
            const ushortT* bp = bbase_p + (size_t)(4 * c + kk) * 6144;
            short8v b0 = *(const short8v*)(bp);
            short8v b1 = *(const short8v*)(bp + 512);
            short8v b2 = *(const short8v*)(bp + 1024);

            const float* ap = &bufp[afrow * 132 + kk * 32 + lg * 8];
            float4 a0 = *(const float4*)ap;
            float4 a1 = *(const float4*)(ap + 4);
            union { short8v s; unsigned int u[4]; } af;
            af.u[0] = pk2bf(a0.x, a0.y); af.u[1] = pk2bf(a0.z, a0.w);
            af.u[2] = pk2bf(a1.x, a1.y); af.u[3] = pk2bf(a1.z, a1.w);

            acc[0] = __builtin_amdgcn_mfma_f32_16x16x32_bf16(af.s, b0, acc[0], 0, 0, 0);
            acc[1] = __builtin_amdgcn_mfma_f32_16x16x32_bf16(af.s, b1, acc[1], 0, 0, 0);
            acc[2] = __builtin_amdgcn_mfma_f32_16x16x32_bf16(af.s, b2, acc[2], 0, 0, 0);
        }
    }
    __syncthreads();   // all reads of sA done before epilogue overlay

    // ---- epilogue: transpose through LDS, emit fragment-packed outputs ----
    const int crow_l = wm * 16 + lg * 4;    // local t row (base of 4)
    ushortT* L16 = (ushortT*)Lqk;
#pragma unroll
    for (int n = 0; n < 3; ++n) {
        const int jb = wn * 3 + n;
        const int j  = jb * 16 + ll;
        const float bj = bias[j];
        float v0 = acc[n][0] + bj, v1 = acc[n][1] + bj;
        float v2 = acc[n][2] + bj, v3 = acc[n][3] + bj;
        if (jb < 8) {   // Q (j 0..63) and K (j 64..127): write along t
            ushortT* p = &L16[crow_l * 136 + j];
            p[0]   = (ushortT)f2bf(v0);
            p[136] = (ushortT)f2bf(v1);
            p[272] = (ushortT)f2bf(v2);
            p[408] = (ushortT)f2bf(v3);
        } else {        // V: d-major, t-pairs
            uintT* p = &Lv[(j - 128) * 20 + (crow_l >> 1)];
            p[0] = pk2bf(v0, v1);
            p[1] = pk2bf(v2, v3);
        }
    }
    __syncthreads();

    const int l2 = tid & 63, ll2 = l2 & 15, lg2 = l2 >> 4;
    if (tid < 256) {
        const int ks = (tid >> 6) & 1, m = tid >> 7;
        uint4 q = *(const uint4*)&Lqk[(m * 16 + ll2) * 68 + ks * 16 + lg2 * 4];
        *(uint4*)&Qf[(((size_t)(row0 >> 4) + m) * 2 + ks) * 512 + l2 * 8] = q;
        const int n = tid >> 6;     // 0..3
        uint4 v = *(const uint4*)&Lv[(n * 16 + ll2) * 20 + lg2 * 4];
        const int bb = row0 >> 11, s32 = (row0 >> 5) & 63;
        *(uint4*)&Vf[((((size_t)bb * 64 + s32) * 4 + n) * 64 + l2) * 8] = v;
    } else {
        const int ks = (tid >> 6) & 1, m = (tid >> 7) & 1;
        uint4 k = *(const uint4*)&Lqk[(m * 16 + ll2) * 68 + 32 + ks * 16 + lg2 * 4];
        *(uint4*)&Kf[(((size_t)(row0 >> 4) + m) * 2 + ks) * 512 + l2 * 8] = k;
    }
}

// ---------------- fused causal attention via bf16 MFMA (no softmax) ----------------
// One 32-row strip per block, 4 waves split the strip's 64-key tiles 4-way.
// Grid 512 = 64 strips x 8 batches, LPT order (si descending, batch-interleaved)
// -> 8 waves/CU steady state, avg ~4 tiles/wave. Combine = verified 4-way path.
__global__ __launch_bounds__(256, 3) void k_attn_mfma(const ushortT* __restrict__ Qf,
                                                      const ushortT* __restrict__ Kf,
                                                      const ushortT* __restrict__ Vf,
                                                      ushortT* __restrict__ hf) {
    __shared__ uintT su[4 * 2 * 16 * 36];   // per-wave S^T bounce, 18.4 KB
    __shared__ float s_o[4][32 * 68];       // per-wave partial O, padded, 34.8 KB

    const int tid = threadIdx.x;
    const int w  = tid >> 6;
    const int l  = tid & 63;
    const int lg = l >> 4;
    const int ll = l & 15;

    const int u = blockIdx.x;
    const int b = u & 7;                    // batch-interleaved
    const int si = 63 - (u >> 3);           // LPT: heaviest strips first

    const int nT  = (si >> 1) + 1;          // 64-key tiles for this strip
    const int qn  = nT >> 2, rem = nT & 3;
    const int t0  = w * qn + (w < rem ? w : rem);
    const int cnt = qn + (w < rem ? 1 : 0);

    const int gq = b * 128 + si * 2;        // global 16-row group of first q rows

    short8v qf[2][2];
#pragma unroll
    for (int mt = 0; mt < 2; ++mt)
#pragma unroll
        for (int ks = 0; ks < 2; ++ks)
            qf[mt][ks] = *(const short8v*)&Qf[(((size_t)gq + mt) * 2 + ks) * 512 + l * 8];

    f32x4 oacc[2][4];
#pragma unroll
    for (int mt = 0; mt < 2; ++mt)
#pragma unroll
        for (int n = 0; n < 4; ++n) oacc[mt][n] = (f32x4){0.f, 0.f, 0.f, 0.f};

    for (int tile = t0; tile < t0 + cnt; ++tile) {
        const int gs = b * 128 + tile * 4;
        short8v kf[4][2];
#pragma unroll
        for (int ms = 0; ms < 4; ++ms) {
            const ushortT* kp = &Kf[(((size_t)gs + ms) * 2) * 512 + l * 8];
            kf[ms][0] = *(const short8v*)kp;
            kf[ms][1] = *(const short8v*)(kp + 512);
        }
        f32x4 sacc[4][2];
#pragma unroll
        for (int ms = 0; ms < 4; ++ms)
#pragma unroll
            for (int mt = 0; mt < 2; ++mt) sacc[ms][mt] = (f32x4){0.f, 0.f, 0.f, 0.f};
#pragma unroll
        for (int ms = 0; ms < 4; ++ms)
#pragma unroll
            for (int mt = 0; mt < 2; ++mt) {
                sacc[ms][mt] = __builtin_amdgcn_mfma_f32_16x16x32_bf16(kf[ms][0], qf[mt][0], sacc[ms][mt], 0, 0, 0);
                sacc[ms][mt] = __builtin_amdgcn_mfma_f32_16x16x32_bf16(kf[ms][1], qf[mt][1], sacc[ms][mt], 0, 0, 0);
            }
        if (tile == nT - 1) {   // causal mask on diagonal tile
#pragma unroll
            for (int ms = 0; ms < 4; ++ms)
#pragma unroll
                for (int mt = 0; mt < 2; ++mt) {
                    const int tg = si * 32 + mt * 16 + ll;
#pragma unroll
                    for (int rr2 = 0; rr2 < 4; ++rr2) {
                        int sg = tile * 64 + ms * 16 + 4 * lg + rr2;
                        if (sg > tg) sacc[ms][mt][rr2] = 0.f;
                    }
                }
        }
        // bounce S^T -> bf16 A-frags (per-wave LDS, no barrier)
#pragma unroll
        for (int mt = 0; mt < 2; ++mt)
#pragma unroll
            for (int ms = 0; ms < 4; ++ms) {
                uint2 pk;
                pk.x = pk2bf(sacc[ms][mt][0], sacc[ms][mt][1]);
                pk.y = pk2bf(sacc[ms][mt][2], sacc[ms][mt][3]);
                *(uint2*)&su[((w * 2 + mt) * 16 + ll) * 36 + ms * 8 + 2 * lg] = pk;
            }
        union { uint4 u4; short8v s; } pa[2][2];
#pragma unroll
        for (int mt = 0; mt < 2; ++mt)
#pragma unroll
            for (int h = 0; h < 2; ++h)
                pa[mt][h].u4 = *(const uint4*)&su[((w * 2 + mt) * 16 + ll) * 36 + h * 16 + lg * 4];

        const int gv = b * 64 + tile * 2;
        short8v vf[2][4];
#pragma unroll
        for (int h = 0; h < 2; ++h)
#pragma unroll
            for (int n = 0; n < 4; ++n)
                vf[h][n] = *(const short8v*)&Vf[((((size_t)gv + h) * 4 + n) * 64 + l) * 8];
#pragma unroll
        for (int mt = 0; mt < 2; ++mt)
#pragma unroll
            for (int n = 0; n < 4; ++n) {
                oacc[mt][n] = __builtin_amdgcn_mfma_f32_16x16x32_bf16(pa[mt][0].s, vf[0][n], oacc[mt][n], 0, 0, 0);
                oacc[mt][n] = __builtin_amdgcn_mfma_f32_16x16x32_bf16(pa[mt][1].s, vf[1][n], oacc[mt][n], 0, 0, 0);
            }
    }

    // partial O to LDS (idle waves contribute zeros)
#pragma unroll
    for (int mt = 0; mt < 2; ++mt)
#pragma unroll
        for (int n = 0; n < 4; ++n)
#pragma unroll
            for (int rr2 = 0; rr2 < 4; ++rr2)
                s_o[w][(mt * 16 + 4 * lg + rr2) * 68 + 16 * n + ll] = oacc[mt][n][rr2];
    __syncthreads();

    // combine 4 waves + emit fragment-packed hf
    const int l2 = tid & 63, ll2 = l2 & 15, lg2 = l2 >> 4;
    const int ks = (tid >> 6) & 1, mt = tid >> 7;
    const int t = mt * 16 + ll2, dd = ks * 32 + lg2 * 8;
    float4 A = {0, 0, 0, 0}, B2 = {0, 0, 0, 0};
#pragma unroll
    for (int w2 = 0; w2 < 4; ++w2) {
        const float4 x = *(const float4*)&s_o[w2][t * 68 + dd];
        const float4 y = *(const float4*)&s_o[w2][t * 68 + dd + 4];
        A.x += x.x; A.y += x.y; A.z += x.z; A.w += x.w;
        B2.x += y.x; B2.y += y.y; B2.z += y.z; B2.w += y.w;
    }
    uint4 o;
    o.x = pk2bf(A.x, A.y);  o.y = pk2bf(A.z, A.w);
    o.z = pk2bf(B2.x, B2.y); o.w = pk2bf(B2.z, B2.w);
    *(uint4*)&hf[(((size_t)(b * 128 + si * 2) + mt) * 2 + ks) * 512 + l2 * 8] = o;
}

// ---------------- out = h @ W2^T + pb via swapped-operand MFMA ----------------
// 32 t-rows per block (two 16-row groups share each w2a fragment load).
__global__ __launch_bounds__(256) void k_proj_mfma(const ushortT* __restrict__ hf,
                                                   const ushortT* __restrict__ w2a,
                                                   const float* __restrict__ pb,
                                                   float* __restrict__ out) {
    const int tid = threadIdx.x;
    const int w = tid >> 6, l = tid & 63;
    const size_t M0 = (size_t)blockIdx.x * 2;

    short8v hA0 = *(const short8v*)&hf[(M0 * 2 + 0) * 512 + l * 8];
    short8v hA1 = *(const short8v*)&hf[(M0 * 2 + 1) * 512 + l * 8];
    short8v hB0 = *(const short8v*)&hf[((M0 + 1) * 2 + 0) * 512 + l * 8];
    short8v hB1 = *(const short8v*)&hf[((M0 + 1) * 2 + 1) * 512 + l * 8];

    const int row = (l >> 4) * 4;
    const int tcol = l & 15;
    const size_t outA = (M0 * 16 + tcol) * Csz;
    const size_t outB = ((M0 + 1) * 16 + tcol) * Csz;

#pragma unroll 2
    for (int m = w * 16; m < w * 16 + 16; ++m) {
        const ushortT* ap = w2a + (size_t)(m * 64 + l) * 8;
        short8v a0 = *(const short8v*)ap;
        short8v a1 = *(const short8v*)(ap + 32768);   // ks=1 plane: 64*64*8
        const int c0 = m * 16 + row;
        const float4 pv = *(const float4*)&pb[c0];

        f32x4 accA = (f32x4){0.f, 0.f, 0.f, 0.f};
        accA = __builtin_amdgcn_mfma_f32_16x16x32_bf16(a0, hA0, accA, 0, 0, 0);
        accA = __builtin_amdgcn_mfma_f32_16x16x32_bf16(a1, hA1, accA, 0, 0, 0);
        f32x4 accB = (f32x4){0.f, 0.f, 0.f, 0.f};
        accB = __builtin_amdgcn_mfma_f32_16x16x32_bf16(a0, hB0, accB, 0, 0, 0);
        accB = __builtin_amdgcn_mfma_f32_16x16x32_bf16(a1, hB1, accB, 0, 0, 0);

        float4 oA, oB;
        oA.x = accA[0] + pv.x; oA.y = accA[1] + pv.y;
        oA.z = accA[2] + pv.z; oA.w = accA[3] + pv.w;
        oB.x = accB[0] + pv.x; oB.y = accB[1] + pv.y;
        oB.z = accB[2] + pv.z; oB.w = accB[3] + pv.w;
        *(float4*)&out[outA + c0] = oA;
        *(float4*)&out[outB + c0] = oB;
    }
}

extern "C" void kernel_launch(void* const* d_in, const int* in_sizes, int n_in,
                              void* d_out, int out_size, void* d_ws, size_t ws_size,
                              hipStream_t stream) {
    const float* ids    = (const float*)d_in[0];
    const float* qkv_w  = (const float*)d_in[1];
    const float* qkv_b  = (const float*)d_in[2];
    const float* proj_w = (const float*)d_in[3];
    const float* proj_b = (const float*)d_in[4];
    float* out = (float*)d_out;

    ushortT* Qf  = (ushortT*)d_ws;          // 2 MB fragment-packed
    ushortT* Kf  = Qf + 16384 * HSsz;       // 2 MB
    ushortT* Vf  = Kf + 16384 * HSsz;       // 2 MB
    ushortT* hf  = Vf + 16384 * HSsz;       // 2 MB
    ushortT* wB  = hf + 16384 * HSsz;       // 384 KB
    ushortT* w2a = wB + 196608;             // 128 KB

    hipLaunchKernelGGL(k_prep,      dim3(128), dim3(256), 0, stream, qkv_w, proj_w, wB, w2a);
    hipLaunchKernelGGL(k_qkv_mfma,  dim3(512), dim3(512), 0, stream, ids, wB, qkv_b, Qf, Kf, Vf);
    hipLaunchKernelGGL(k_attn_mfma, dim3(512), dim3(256), 0, stream, Qf, Kf, Vf, hf);
    hipLaunchKernelGGL(k_proj_mfma, dim3(512), dim3(256), 0, stream, hf, w2a, proj_b, out);
}